// Round 4
// baseline (187.913 us; speedup 1.0000x reference)
//
#include <hip/hip_runtime.h>
#include <math.h>
#include <float.h>

#define BS 256
#define CHUNK 4608          // gt rows per LDS tile (36 KB) -> 4 blocks/CU; covers
                            // ~all blocks (max block total ~4455) in ONE pass
typedef unsigned int u32;

// ws layout (nb = 1024):
//   [0, 4K)        int blockSums[nb]
//   [4K, 4K+4)     u32 done            (zeroed by block_sum block 0; no memset node)
//   [8K, 24K)      float4 partials[nb] (lp, la, lw, ls per block)

__global__ void block_sum_kernel(const int* __restrict__ counts,
                                 int* __restrict__ blockSums,
                                 u32* __restrict__ done, int N) {
    int i = blockIdx.x * BS + threadIdx.x;
    int v = (i < N) ? counts[i] : 0;
    for (int o = 32; o > 0; o >>= 1) v += __shfl_down(v, o, 64);
    __shared__ int ws[BS / 64];
    int lane = threadIdx.x & 63, w = threadIdx.x >> 6;
    if (lane == 0) ws[w] = v;
    __syncthreads();
    if (threadIdx.x == 0) {
        int s = 0;
        for (int ww = 0; ww < BS / 64; ++ww) s += ws[ww];
        blockSums[blockIdx.x] = s;
        if (blockIdx.x == 0) *done = 0;   // kernel-boundary ordering covers fused
    }
}

// Block b owns pred rows [b*256, b*256+256) and their contiguous gt range.
// v4: self-scan base (no scan kernel), single-pass LDS staging (CHUNK=4608),
// and the finalize reduce folded in via a last-block-done ticket (one
// atomicAdd per block at ramp-down -- no spinning, no pre-loop sync).
__global__ void __launch_bounds__(BS)
fused_kernel(const float* __restrict__ pred, const float* __restrict__ gt,
             const int* __restrict__ counts, const int* __restrict__ blockSums,
             float* __restrict__ partials, u32* __restrict__ done,
             float* __restrict__ out, int N) {
    const int t = threadIdx.x;
    const int b = blockIdx.x;
    const int nb = gridDim.x;
    const int i = b * BS + t;
    const int lane = t & 63, w = t >> 6;

    __shared__ float2 chunkXY[CHUNK];   // 36864 B
    __shared__ int waveTot[BS / 64];
    __shared__ int basePart[BS / 64];
    __shared__ int sTotal;
    __shared__ int sFlag;
    __shared__ float red[BS / 64][4];
    __shared__ double dred[BS / 64][4];

    // ---- intra-block exclusive scan of counts ----
    const int c = (i < N) ? counts[i] : 0;
    int incl = c;
    for (int o = 1; o < 64; o <<= 1) {
        int x = __shfl_up(incl, o, 64);
        if (lane >= o) incl += x;
    }
    if (lane == 63) waveTot[w] = incl;

    // ---- self-scan of blockSums[0..b): my global gt base ----
    int acc = 0;
#pragma unroll
    for (int k = 0; k < 4; ++k) {
        const int idx = t + BS * k;
        if (idx < b) acc += blockSums[idx];
    }
    for (int o = 32; o > 0; o >>= 1) acc += __shfl_down(acc, o, 64);
    if (lane == 0) basePart[w] = acc;
    __syncthreads();

    int wbase = 0;
    for (int ww = 0; ww < w; ++ww) wbase += waveTot[ww];
    const int myStart = wbase + incl - c;       // local gt row of my segment
    const int myEnd = myStart + c;
    const int base = basePart[0] + basePart[1] + basePart[2] + basePart[3];
    if (t == BS - 1) sTotal = myEnd;
    __syncthreads();

    const int blockTotal = sTotal;
    const float2* gxy = reinterpret_cast<const float2*>(gt);

    const float2 myp = (i < N)
        ? reinterpret_cast<const float2*>(pred)[(size_t)i * 3]
        : make_float2(0.f, 0.f);

    float best = FLT_MAX;
    int bestRow = 0;                            // global gt row of nearest

    for (int chunkLo = 0; chunkLo < blockTotal; chunkLo += CHUNK) {
        // coalesced stage: 18 independent predicated loads per thread
#pragma unroll
        for (int u = 0; u < CHUNK / BS; ++u) {
            const int j = u * BS + t;
            const int gj = chunkLo + j;
            if (gj < blockTotal) chunkXY[j] = gxy[(size_t)(base + gj) * 3];
        }
        __syncthreads();
        // my segment ∩ this chunk; ascending order + strict < keeps the
        // lowest global row on d2 ties, matching the reference tie-break
        const int lo = myStart > chunkLo ? myStart : chunkLo;
        const int hiLim = chunkLo + CHUNK;
        const int hi = myEnd < hiLim ? myEnd : hiLim;
        for (int j = lo; j < hi; ++j) {
            const float2 g = chunkXY[j - chunkLo];
            const float dx = myp.x - g.x, dy = myp.y - g.y;
            const float d2 = dx * dx + dy * dy;
            if (d2 < best) { best = d2; bestRow = base + j; }
        }
        __syncthreads();
    }

    // ---- per-pred epilogue ----
    float lp = 0.f, la = 0.f, lw = 0.f, ls = 0.f;
    if (i < N && c > 0) {
        lp = 1.0f - expf(-best / 0.045f);  // max resp == exp(-min d2/(2 sigma^2))

        const float* p = pred + (size_t)i * 6;
        const float2 p23 = *reinterpret_cast<const float2*>(p + 2);
        const float2 p45 = *reinterpret_cast<const float2*>(p + 4);
        const float* ng = gt + (size_t)bestRow * 6;
        const float2 g23 = *reinterpret_cast<const float2*>(ng + 2);
        const float2 g45 = *reinterpret_cast<const float2*>(ng + 4);

        la = fabsf(p23.x - g23.x) + fabsf(p23.y - g23.y);
        const float d = p45.x - g45.x;
        const float ad = fabsf(d);
        lw = (ad < 1.0f) ? 0.5f * d * d : ad - 0.5f;
        const float x = p45.y;
        if (g45.y > 0.0f) {
            ls = fmaxf(x, 0.0f) - x * g45.y + log1pf(expf(-fabsf(x)));
        }
    }

    for (int o = 32; o > 0; o >>= 1) {
        lp += __shfl_down(lp, o, 64);
        la += __shfl_down(la, o, 64);
        lw += __shfl_down(lw, o, 64);
        ls += __shfl_down(ls, o, 64);
    }
    if (lane == 0) { red[w][0] = lp; red[w][1] = la; red[w][2] = lw; red[w][3] = ls; }
    __syncthreads();
    if (t == 0) {
        float s0 = 0, s1 = 0, s2 = 0, s3 = 0;
        for (int ww = 0; ww < BS / 64; ++ww) {
            s0 += red[ww][0]; s1 += red[ww][1]; s2 += red[ww][2]; s3 += red[ww][3];
        }
        // RMW stores: guaranteed visible at device coherence point
        atomicExch(&partials[b * 4 + 0], s0);
        atomicExch(&partials[b * 4 + 1], s1);
        atomicExch(&partials[b * 4 + 2], s2);
        atomicExch(&partials[b * 4 + 3], s3);
        __threadfence();
        const u32 old = atomicAdd(done, 1u);
        sFlag = (old == (u32)(nb - 1)) ? 1 : 0;
    }
    __syncthreads();

    // ---- final reduce by the last-finishing block ----
    // (identical f64 accumulation order to the proven round-1 finalize:
    //  rows t, t+256, t+512, t+768 -> shfl_down -> 4 wave partials -> serial)
    if (sFlag) {
        __threadfence();
        double a0 = 0, a1 = 0, a2 = 0, a3 = 0;
        for (int r = t; r < nb; r += BS) {
            a0 += (double)atomicAdd(&partials[r * 4 + 0], 0.0f);
            a1 += (double)atomicAdd(&partials[r * 4 + 1], 0.0f);
            a2 += (double)atomicAdd(&partials[r * 4 + 2], 0.0f);
            a3 += (double)atomicAdd(&partials[r * 4 + 3], 0.0f);
        }
        for (int o = 32; o > 0; o >>= 1) {
            a0 += __shfl_down(a0, o, 64);
            a1 += __shfl_down(a1, o, 64);
            a2 += __shfl_down(a2, o, 64);
            a3 += __shfl_down(a3, o, 64);
        }
        if (lane == 0) { dred[w][0] = a0; dred[w][1] = a1; dred[w][2] = a2; dred[w][3] = a3; }
        __syncthreads();
        if (t == 0) {
            double t0 = 0, t1 = 0, t2 = 0, t3 = 0;
            for (int ww = 0; ww < BS / 64; ++ww) {
                t0 += dred[ww][0]; t1 += dred[ww][1]; t2 += dred[ww][2]; t3 += dred[ww][3];
            }
            const double inv = 1.0 / (double)N;
            const float flp = (float)(t0 * inv);
            const float fla = (float)(t1 * inv);
            const float flw = (float)(t2 * inv);
            const float fls = (float)(t3 * inv);
            out[0] = flp; out[1] = fla; out[2] = flw; out[3] = fls;
            out[4] = flp + fla + flw + 0.5f * fls;
        }
    }
}

extern "C" void kernel_launch(void* const* d_in, const int* in_sizes, int n_in,
                              void* d_out, int out_size, void* d_ws, size_t ws_size,
                              hipStream_t stream) {
    const float* pred = (const float*)d_in[0];
    const float* gt = (const float*)d_in[1];
    const int* counts = (const int*)d_in[2];
    float* out = (float*)d_out;

    const int N = in_sizes[2];
    const int numBlocks = (N + BS - 1) / BS;  // 1024

    int* blockSums = (int*)d_ws;
    u32* done = (u32*)((char*)d_ws + 4096);
    float* partials = (float*)((char*)d_ws + 8192);

    block_sum_kernel<<<numBlocks, BS, 0, stream>>>(counts, blockSums, done, N);
    fused_kernel<<<numBlocks, BS, 0, stream>>>(pred, gt, counts, blockSums,
                                               partials, done, out, N);
}

// Round 5
// 179.654 us; speedup vs baseline: 1.0460x; 1.0460x over previous
//
#include <hip/hip_runtime.h>
#include <math.h>
#include <float.h>

#define BS 256
#define MAXC 31             // counts are in [0, 31]
typedef unsigned int u32;

// ws layout (nb = 1024):
//   [0, 4K)        int blockSums[nb]
//   [8K, 24K)      float4 partials[nb]   (lp, la, lw, ls per block)

__global__ void block_sum_kernel(const int* __restrict__ counts,
                                 int* __restrict__ blockSums, int N) {
    int i = blockIdx.x * BS + threadIdx.x;
    int v = (i < N) ? counts[i] : 0;
    for (int o = 32; o > 0; o >>= 1) v += __shfl_down(v, o, 64);
    __shared__ int ws[BS / 64];
    int lane = threadIdx.x & 63, w = threadIdx.x >> 6;
    if (lane == 0) ws[w] = v;
    __syncthreads();
    if (threadIdx.x == 0) {
        int s = 0;
        for (int ww = 0; ww < BS / 64; ++ww) s += ws[ww];
        blockSums[blockIdx.x] = s;
    }
}

// v5: NO LDS staging, NO barriers in the hot path. Each thread's gt segment
// (<=31 rows) is private to that thread, so LDS staging adds only barrier
// stalls. Fully-unrolled predicated scan: 31 independent global loads per
// thread, ascending row order + strict < == reference tie-break (lowest row).
// LDS ~100 B -> 8 blocks/CU, 32 waves/CU: pure streaming with max TLP.
__global__ void __launch_bounds__(BS)
fused_kernel(const float* __restrict__ pred, const float* __restrict__ gt,
             const int* __restrict__ counts, const int* __restrict__ blockSums,
             float4* __restrict__ partials, int N) {
    const int t = threadIdx.x;
    const int b = blockIdx.x;
    const int i = b * BS + t;
    const int lane = t & 63, w = t >> 6;

    __shared__ int waveTot[BS / 64];
    __shared__ int basePart[BS / 64];
    __shared__ float red[BS / 64][4];

    // ---- intra-block exclusive scan of counts ----
    const int c = (i < N) ? counts[i] : 0;
    int incl = c;
    for (int o = 1; o < 64; o <<= 1) {
        int x = __shfl_up(incl, o, 64);
        if (lane >= o) incl += x;
    }
    if (lane == 63) waveTot[w] = incl;

    // ---- self-scan of blockSums[0..b): my global gt base (L2-hot) ----
    int acc = 0;
#pragma unroll
    for (int k = 0; k < 4; ++k) {
        const int idx = t + BS * k;
        if (idx < b) acc += blockSums[idx];
    }
    for (int o = 32; o > 0; o >>= 1) acc += __shfl_down(acc, o, 64);
    if (lane == 0) basePart[w] = acc;
    __syncthreads();

    int wbase = 0;
    for (int ww = 0; ww < w; ++ww) wbase += waveTot[ww];
    const int base = basePart[0] + basePart[1] + basePart[2] + basePart[3];
    const int gStart = base + wbase + incl - c;   // my first global gt row

    const float2* gxy = reinterpret_cast<const float2*>(gt);
    const float2 myp = (i < N)
        ? reinterpret_cast<const float2*>(pred)[(size_t)i * 3]
        : make_float2(0.f, 0.f);

    float best = FLT_MAX;
    int bestRow = 0;                              // global gt row of nearest

    // ---- direct segment scan: 31 predicated independent loads ----
#pragma unroll
    for (int j = 0; j < MAXC; ++j) {
        if (j < c) {
            const float2 g = gxy[(size_t)(gStart + j) * 3];
            const float dx = myp.x - g.x, dy = myp.y - g.y;
            const float d2 = dx * dx + dy * dy;
            if (d2 < best) { best = d2; bestRow = gStart + j; }
        }
    }

    // ---- per-pred epilogue ----
    float lp = 0.f, la = 0.f, lw = 0.f, ls = 0.f;
    if (i < N && c > 0) {
        lp = 1.0f - expf(-best / 0.045f);  // max resp == exp(-min d2/(2 sigma^2))

        const float* p = pred + (size_t)i * 6;
        const float2 p23 = *reinterpret_cast<const float2*>(p + 2);
        const float2 p45 = *reinterpret_cast<const float2*>(p + 4);
        const float* ng = gt + (size_t)bestRow * 6;
        const float2 g23 = *reinterpret_cast<const float2*>(ng + 2);
        const float2 g45 = *reinterpret_cast<const float2*>(ng + 4);

        la = fabsf(p23.x - g23.x) + fabsf(p23.y - g23.y);
        const float d = p45.x - g45.x;
        const float ad = fabsf(d);
        lw = (ad < 1.0f) ? 0.5f * d * d : ad - 0.5f;
        const float x = p45.y;
        if (g45.y > 0.0f) {
            ls = fmaxf(x, 0.0f) - x * g45.y + log1pf(expf(-fabsf(x)));
        }
    }

    for (int o = 32; o > 0; o >>= 1) {
        lp += __shfl_down(lp, o, 64);
        la += __shfl_down(la, o, 64);
        lw += __shfl_down(lw, o, 64);
        ls += __shfl_down(ls, o, 64);
    }
    if (lane == 0) { red[w][0] = lp; red[w][1] = la; red[w][2] = lw; red[w][3] = ls; }
    __syncthreads();
    if (t == 0) {
        float s0 = 0, s1 = 0, s2 = 0, s3 = 0;
        for (int ww = 0; ww < BS / 64; ++ww) {
            s0 += red[ww][0]; s1 += red[ww][1]; s2 += red[ww][2]; s3 += red[ww][3];
        }
        partials[b] = make_float4(s0, s1, s2, s3);  // distinct slot: no atomics
    }
}

// Reduce 1024 per-block partials in one block; f64 accumulation.
__global__ void finalize_kernel(const float4* __restrict__ partials,
                                float* __restrict__ out, int nb, int N) {
    const int t = threadIdx.x;
    const int lane = t & 63, w = t >> 6;
    double s0 = 0, s1 = 0, s2 = 0, s3 = 0;
    if (t < nb) {
        const float4 v = partials[t];
        s0 = v.x; s1 = v.y; s2 = v.z; s3 = v.w;
    }
    for (int o = 32; o > 0; o >>= 1) {
        s0 += __shfl_down(s0, o, 64);
        s1 += __shfl_down(s1, o, 64);
        s2 += __shfl_down(s2, o, 64);
        s3 += __shfl_down(s3, o, 64);
    }
    __shared__ double red[16][4];
    if (lane == 0) { red[w][0] = s0; red[w][1] = s1; red[w][2] = s2; red[w][3] = s3; }
    __syncthreads();
    if (t == 0) {
        double t0 = 0, t1 = 0, t2 = 0, t3 = 0;
        for (int ww = 0; ww < blockDim.x / 64; ++ww) {
            t0 += red[ww][0]; t1 += red[ww][1]; t2 += red[ww][2]; t3 += red[ww][3];
        }
        const double inv = 1.0 / (double)N;
        const float lp = (float)(t0 * inv);
        const float la = (float)(t1 * inv);
        const float lw = (float)(t2 * inv);
        const float ls = (float)(t3 * inv);
        out[0] = lp; out[1] = la; out[2] = lw; out[3] = ls;
        out[4] = lp + la + lw + 0.5f * ls;
    }
}

extern "C" void kernel_launch(void* const* d_in, const int* in_sizes, int n_in,
                              void* d_out, int out_size, void* d_ws, size_t ws_size,
                              hipStream_t stream) {
    const float* pred = (const float*)d_in[0];
    const float* gt = (const float*)d_in[1];
    const int* counts = (const int*)d_in[2];
    float* out = (float*)d_out;

    const int N = in_sizes[2];
    const int numBlocks = (N + BS - 1) / BS;  // 1024

    int* blockSums = (int*)d_ws;
    float4* partials = (float4*)((char*)d_ws + 8192);

    block_sum_kernel<<<numBlocks, BS, 0, stream>>>(counts, blockSums, N);
    fused_kernel<<<numBlocks, BS, 0, stream>>>(pred, gt, counts, blockSums,
                                               partials, N);
    finalize_kernel<<<1, 1024, 0, stream>>>(partials, out, numBlocks, N);
}

// Round 6
// 168.338 us; speedup vs baseline: 1.1163x; 1.0672x over previous
//
#include <hip/hip_runtime.h>
#include <math.h>
#include <float.h>

#define BS 256
#define MAXC 31                 // counts are in [0, 31]
#define CH 1536                 // gt rows per LDS chunk: 1536*24 B = 36864 B
#define CHF4 (CH * 24 / 16)     // 2304 float4 per chunk
#define LPT (CHF4 / BS)         // 9 float4 loads per thread per chunk

// ws layout (nb = 1024):
//   [0, 4K)        int blockSums[nb]
//   [8K, 24K)      float4 partials[nb]   (lp, la, lw, ls per block)

__global__ void block_sum_kernel(const int* __restrict__ counts,
                                 int* __restrict__ blockSums, int N) {
    int i = blockIdx.x * BS + threadIdx.x;
    int v = (i < N) ? counts[i] : 0;
    for (int o = 32; o > 0; o >>= 1) v += __shfl_down(v, o, 64);
    __shared__ int ws[BS / 64];
    int lane = threadIdx.x & 63, w = threadIdx.x >> 6;
    if (lane == 0) ws[w] = v;
    __syncthreads();
    if (threadIdx.x == 0) {
        int s = 0;
        for (int ww = 0; ww < BS / 64; ++ww) s += ws[ww];
        blockSums[blockIdx.x] = s;
    }
}

// v6: the load path is the bottleneck (R4/R5: warm replays as slow as cold ->
// line-transaction-bound, not HBM-bound). Stage the block's RAW gt range
// (full 24 B rows) into LDS via perfectly dense float4 loads: 8 lines per
// wave-instr, 100% utilization, each line touched once. Consumers scan their
// private segment's xy from LDS; the best row's remaining fields are captured
// from LDS at improvement time (ascending order + strict < == reference
// tie-break), eliminating the epilogue's random global gather.
__global__ void __launch_bounds__(BS)
fused_kernel(const float* __restrict__ pred, const float* __restrict__ gt,
             const int* __restrict__ counts, const int* __restrict__ blockSums,
             float4* __restrict__ partials, int N) {
    const int t = threadIdx.x;
    const int b = blockIdx.x;
    const int i = b * BS + t;
    const int lane = t & 63, w = t >> 6;

    __shared__ float4 chunk4[CHF4 + 1];   // 36880 B (raw rows; +1 f4 tail slack)
    __shared__ int waveTot[BS / 64];
    __shared__ int basePart[BS / 64];
    __shared__ int sTotal;
    __shared__ float red[BS / 64][4];

    // ---- intra-block exclusive scan of counts ----
    const int c = (i < N) ? counts[i] : 0;
    int incl = c;
    for (int o = 1; o < 64; o <<= 1) {
        int x = __shfl_up(incl, o, 64);
        if (lane >= o) incl += x;
    }
    if (lane == 63) waveTot[w] = incl;

    // ---- self-scan of blockSums[0..b): my global gt base (L2-hot) ----
    int acc = 0;
#pragma unroll
    for (int k = 0; k < 4; ++k) {
        const int idx = t + BS * k;
        if (idx < b) acc += blockSums[idx];
    }
    for (int o = 32; o > 0; o >>= 1) acc += __shfl_down(acc, o, 64);
    if (lane == 0) basePart[w] = acc;
    __syncthreads();

    int wbase = 0;
    for (int ww = 0; ww < w; ++ww) wbase += waveTot[ww];
    const int base = basePart[0] + basePart[1] + basePart[2] + basePart[3];
    const int myStart = wbase + incl - c;   // first local row of my segment
    const int myEnd = myStart + c;
    if (t == BS - 1) sTotal = myEnd;
    __syncthreads();

    const int blockTotal = sTotal;
    const int pad = base & 1;               // round start DOWN to even row:
    const int totalRows = blockTotal + pad; // byte start startRow*24 % 16 == 0
    const size_t startByte = (size_t)(base - pad) * 24;
    const float4* gt4 = reinterpret_cast<const float4*>(
        reinterpret_cast<const char*>(gt) + startByte);
    const float2* cf2 = reinterpret_cast<const float2*>(chunk4);

    const float2 myp = (i < N)
        ? reinterpret_cast<const float2*>(pred)[(size_t)i * 3]
        : make_float2(0.f, 0.f);

    float best = FLT_MAX;
    float2 bg23 = make_float2(0.f, 0.f);    // captured fields of current argmin
    float2 bg45 = make_float2(0.f, 0.f);

    for (int row0 = 0; row0 < totalRows; row0 += CH) {
        const int rowsHere = min(CH, totalRows - row0);
        const int bytesHere = rowsHere * 24;
        const int nf4 = bytesHere >> 4;
        const int f4Base = row0 * 3 / 2;    // row0 even (CH even) -> exact
        // dense stage: up to 9 fully-coalesced float4 loads per thread
#pragma unroll
        for (int u = 0; u < LPT; ++u) {
            const int idx = u * BS + t;
            if (idx < nf4) chunk4[idx] = gt4[f4Base + idx];
        }
        if (t == 0 && (bytesHere & 15)) {   // odd-row tail: one 8 B load
            reinterpret_cast<float2*>(chunk4)[nf4 * 2] =
                *reinterpret_cast<const float2*>(
                    reinterpret_cast<const char*>(gt) + startByte +
                    (size_t)row0 * 24 + (size_t)nf4 * 16);
        }
        __syncthreads();

        // my segment ∩ this chunk (segments span <= 2 chunks since c <= 31)
        const int cLo = row0 - pad;                 // chunk range, base-relative
        const int cHi = cLo + rowsHere;
        const int lo = myStart > cLo ? myStart : cLo;
        const int hi = myEnd < cHi ? myEnd : cHi;
        for (int j = lo; j < hi; ++j) {
            const int rr = j + pad - row0;          // LDS row index
            const float2 g = cf2[rr * 3];
            const float dx = myp.x - g.x, dy = myp.y - g.y;
            const float d2 = dx * dx + dy * dy;
            if (d2 < best) {
                best = d2;
                bg23 = cf2[rr * 3 + 1];             // fields 2,3 of argmin row
                bg45 = cf2[rr * 3 + 2];             // fields 4,5
            }
        }
        if (row0 + CH < totalRows) __syncthreads(); // before overwrite
    }

    // ---- per-pred epilogue (no global gather: fields already captured) ----
    float lp = 0.f, la = 0.f, lw = 0.f, ls = 0.f;
    if (i < N && c > 0) {
        lp = 1.0f - expf(-best / 0.045f);  // max resp == exp(-min d2/(2 sigma^2))

        const float* p = pred + (size_t)i * 6;
        const float2 p23 = *reinterpret_cast<const float2*>(p + 2);
        const float2 p45 = *reinterpret_cast<const float2*>(p + 4);

        la = fabsf(p23.x - bg23.x) + fabsf(p23.y - bg23.y);
        const float d = p45.x - bg45.x;
        const float ad = fabsf(d);
        lw = (ad < 1.0f) ? 0.5f * d * d : ad - 0.5f;
        const float x = p45.y;
        if (bg45.y > 0.0f) {
            ls = fmaxf(x, 0.0f) - x * bg45.y + log1pf(expf(-fabsf(x)));
        }
    }

    for (int o = 32; o > 0; o >>= 1) {
        lp += __shfl_down(lp, o, 64);
        la += __shfl_down(la, o, 64);
        lw += __shfl_down(lw, o, 64);
        ls += __shfl_down(ls, o, 64);
    }
    if (lane == 0) { red[w][0] = lp; red[w][1] = la; red[w][2] = lw; red[w][3] = ls; }
    __syncthreads();
    if (t == 0) {
        float s0 = 0, s1 = 0, s2 = 0, s3 = 0;
        for (int ww = 0; ww < BS / 64; ++ww) {
            s0 += red[ww][0]; s1 += red[ww][1]; s2 += red[ww][2]; s3 += red[ww][3];
        }
        partials[b] = make_float4(s0, s1, s2, s3);  // distinct slot: no atomics
    }
}

// Reduce 1024 per-block partials in one block; f64 accumulation.
__global__ void finalize_kernel(const float4* __restrict__ partials,
                                float* __restrict__ out, int nb, int N) {
    const int t = threadIdx.x;
    const int lane = t & 63, w = t >> 6;
    double s0 = 0, s1 = 0, s2 = 0, s3 = 0;
    if (t < nb) {
        const float4 v = partials[t];
        s0 = v.x; s1 = v.y; s2 = v.z; s3 = v.w;
    }
    for (int o = 32; o > 0; o >>= 1) {
        s0 += __shfl_down(s0, o, 64);
        s1 += __shfl_down(s1, o, 64);
        s2 += __shfl_down(s2, o, 64);
        s3 += __shfl_down(s3, o, 64);
    }
    __shared__ double red[16][4];
    if (lane == 0) { red[w][0] = s0; red[w][1] = s1; red[w][2] = s2; red[w][3] = s3; }
    __syncthreads();
    if (t == 0) {
        double t0 = 0, t1 = 0, t2 = 0, t3 = 0;
        for (int ww = 0; ww < blockDim.x / 64; ++ww) {
            t0 += red[ww][0]; t1 += red[ww][1]; t2 += red[ww][2]; t3 += red[ww][3];
        }
        const double inv = 1.0 / (double)N;
        const float lp = (float)(t0 * inv);
        const float la = (float)(t1 * inv);
        const float lw = (float)(t2 * inv);
        const float ls = (float)(t3 * inv);
        out[0] = lp; out[1] = la; out[2] = lw; out[3] = ls;
        out[4] = lp + la + lw + 0.5f * ls;
    }
}

extern "C" void kernel_launch(void* const* d_in, const int* in_sizes, int n_in,
                              void* d_out, int out_size, void* d_ws, size_t ws_size,
                              hipStream_t stream) {
    const float* pred = (const float*)d_in[0];
    const float* gt = (const float*)d_in[1];
    const int* counts = (const int*)d_in[2];
    float* out = (float*)d_out;

    const int N = in_sizes[2];
    const int numBlocks = (N + BS - 1) / BS;  // 1024

    int* blockSums = (int*)d_ws;
    float4* partials = (float4*)((char*)d_ws + 8192);

    block_sum_kernel<<<numBlocks, BS, 0, stream>>>(counts, blockSums, N);
    fused_kernel<<<numBlocks, BS, 0, stream>>>(pred, gt, counts, blockSums,
                                               partials, N);
    finalize_kernel<<<1, 1024, 0, stream>>>(partials, out, numBlocks, N);
}